// Round 11
// baseline (183.269 us; speedup 1.0000x reference)
//
#include <hip/hip_runtime.h>
#include <hip/hip_bf16.h>

typedef __attribute__((ext_vector_type(8))) __bf16 bf16x8;
typedef __attribute__((ext_vector_type(16))) float f32x16;

#define SCALE_L2E 14.4269504088896f // 10 * log2(e)
#define NTOT 32768

#define AS_GLOBAL __attribute__((address_space(1)))
#define AS_LDS    __attribute__((address_space(3)))

__device__ inline void async_copy16(const void* g, void* l) {
    __builtin_amdgcn_global_load_lds((const AS_GLOBAL void*)g, (AS_LDS void*)l, 16, 0, 0);
}

// device-coherent float load (bypasses the reader XCD's non-coherent L2)
__device__ inline float aload(const float* p) {
    return __hip_atomic_load(p, __ATOMIC_RELAXED, __HIP_MEMORY_SCOPE_AGENT);
}

// ---------------------------------------------------------------------------
// bf16 pack helpers (RNE)
// ---------------------------------------------------------------------------
__device__ inline unsigned int f2bf(float f) {
    unsigned int u = __builtin_bit_cast(unsigned int, f);
    u += 0x7fffu + ((u >> 16) & 1u);
    return u >> 16;
}

__device__ inline uint4 pack8(float4 x, float4 y, float s) {
    uint4 r;
    r.x = f2bf(x.x * s) | (f2bf(x.y * s) << 16);
    r.y = f2bf(x.z * s) | (f2bf(x.w * s) << 16);
    r.z = f2bf(y.x * s) | (f2bf(y.y * s) << 16);
    r.w = f2bf(y.z * s) | (f2bf(y.w * s) << 16);
    return r;
}

__device__ inline float dot8(float4 x, float4 y) {
    return x.x*y.x + x.y*y.y + x.z*y.z + x.w*y.w;
}

// ---------------------------------------------------------------------------
// Kernel 1: L2-normalize -> bf16 FRAGMENT-MAJOR + fp32 diag partials.
// E1 is PRE-SCALED by 10*log2(e) so gemm's epilogue is exp2(acc).
// Coalesced E-stores via 32KB XOR-swizzled LDS transpose (r10, -13.5us).
// Also zeroes scalars + the 193 group counters for gemm's fused finalize.
// ---------------------------------------------------------------------------
__global__ __launch_bounds__(256) void nrm_kernel(
        const float* __restrict__ A, const float* __restrict__ B,
        uint4* __restrict__ E1f, uint4* __restrict__ E2f,
        float* __restrict__ diagPart, float* __restrict__ scalars,
        unsigned int* __restrict__ cnts) {
    __shared__ uint4 E1lds[1024];   // 16 KB
    __shared__ uint4 E2lds[1024];   // 16 KB
    __shared__ float part[4];

    const int tid = threadIdx.x, w = tid >> 6, l = tid & 63;
    const int q = l & 31, h = l >> 5;
    const int wid = blockIdx.x * 4 + w;            // 0..4095, 8 rows each

    const float4* A4 = (const float4*)A + ((size_t)wid * 8 + h) * 64 + q * 2;
    const float4* B4 = (const float4*)B + ((size_t)wid * 8 + h) * 64 + q * 2;

    float4 a[8], bb[8];
    #pragma unroll
    for (int i = 0; i < 4; ++i) {                  // all loads up front (MLP)
        a[2*i]    = A4[i * 128];
        a[2*i+1]  = A4[i * 128 + 1];
        bb[2*i]   = B4[i * 128];
        bb[2*i+1] = B4[i * 128 + 1];
    }

    float ddAcc = 0.f;
    #pragma unroll
    for (int i = 0; i < 4; ++i) {
        float sa = dot8(a[2*i], a[2*i]) + dot8(a[2*i+1], a[2*i+1]);
        float sb = dot8(bb[2*i], bb[2*i]) + dot8(bb[2*i+1], bb[2*i+1]);
        float dd = dot8(a[2*i], bb[2*i]) + dot8(a[2*i+1], bb[2*i+1]);
        #pragma unroll
        for (int off = 1; off <= 16; off <<= 1) {
            sa += __shfl_xor(sa, off);
            sb += __shfl_xor(sb, off);
            dd += __shfl_xor(dd, off);
        }
        const float ia = 1.0f / fmaxf(sqrtf(sa), 1e-12f);
        const float ib = 1.0f / fmaxf(sqrtf(sb), 1e-12f);
        if (q == 0) ddAcc += dd * ia * ib * 10.0f;

        // LDS transpose staging: idx within this block's 32-row group
        const int row32 = w * 8 + i * 2 + h;                 // 0..31
        const int idx   = (q >> 1) * 64 + (q & 1) * 32 + row32;
        const int idxs  = idx ^ ((idx >> 5) & 7);            // bank swizzle
        E1lds[idxs] = pack8(a[2*i], a[2*i+1], ia * SCALE_L2E);  // pre-scaled
        E2lds[idxs] = pack8(bb[2*i], bb[2*i+1], ib);
    }

    #pragma unroll
    for (int off = 1; off <= 32; off <<= 1) ddAcc += __shfl_xor(ddAcc, off);
    if (l == 0) part[w] = ddAcc;
    __syncthreads();   // part[] + E-lds complete

    // coalesced write-out: this block's group is uint4[blockIdx*1024 ..)
    {
        uint4* g1 = E1f + (size_t)blockIdx.x * 1024;
        uint4* g2 = E2f + (size_t)blockIdx.x * 1024;
        #pragma unroll
        for (int j = 0; j < 4; ++j) {
            const int t = j * 256 + tid;
            const int ts = t ^ ((t >> 5) & 7);
            g1[t] = E1lds[ts];
            g2[t] = E2lds[ts];
        }
    }

    if (tid == 0) diagPart[blockIdx.x] = part[0] + part[1] + part[2] + part[3];
    if (blockIdx.x == 0) {
        if (tid == 0) scalars[0] = 0.f;
        if (tid < 193) cnts[tid] = 0u;   // cntRow[128] | cntCol[64] | cnt2[1]
    }
}

// ---------------------------------------------------------------------------
// Kernel 2: fused GEMM + exp + row/col partials + FINALIZE. 512 blocks,
// 4 waves. Block: 256 rows x 512 cols; wave: 64 rows (af0/af1 in regs).
// Core loop = EXACT r3 (44.1us): intrinsic MFMAs, (256,2), spill tolerated.
//
// FUSED FINALIZE (replaces fin_kernel): per-group last-done tails.
//  - row log-sums for (b,rt) need only its 4 ct-blocks -> 4th arrival does
//    256 rows; col log-sums for (b,ct) need its 8 rt-blocks -> 8th arrival
//    does 512 cols. Tails overlap still-running gemm blocks.
//  - 192nd group contribution (cnt2, fin's scalars+fence+counter pattern)
//    adds the diag term and writes out[0].
//  - Coherence: writers __threadfence() (L2 writeback) before the group
//    atomicAdd; readers fence after observing the count and use agent-scope
//    loads for partials (bypass possibly-stale local L2).
// ---------------------------------------------------------------------------
__global__ __launch_bounds__(256, 2) void gemm_kernel(
        const bf16x8* __restrict__ E1f, const uint4* __restrict__ E2f,
        float* __restrict__ colPart, float* __restrict__ rowPart,
        const float* __restrict__ diagPart, float* __restrict__ scalars,
        unsigned int* __restrict__ cnts, float* __restrict__ out) {
    __shared__ bf16x8 Bbuf[2][2048];   // 2 x 32 KB (64 cols each)
    __shared__ float colLDS[2048];     // 4 per-wave slices of 512
    __shared__ float redbuf[4];
    __shared__ unsigned int rrS, rcS, isLastS;

    const int tid = threadIdx.x, w = tid >> 6, l = tid & 63;
    const int b = blockIdx.x & 15;             // XCD = b&7 (L2 pinning)
    const int ct = (blockIdx.x >> 4) & 3, rt = blockIdx.x >> 6;

    unsigned int* cntRow = cnts;               // [128] (b*8+rt)
    unsigned int* cntCol = cnts + 128;         // [64]  (b*4+ct)
    unsigned int* cnt2   = cnts + 192;         // [1]

    for (int i = l; i < 512; i += 64) colLDS[w * 512 + i] = 0.f;

    const uint4* Bb = E2f + (size_t)b * 65536 + (size_t)ct * 16384 + l;

    // stage 64-col group sg into Bbuf[buf]; wave w covers 8 chunk-rows
    auto stage = [&](int buf, int sg) {
        const uint4* src = Bb + (size_t)sg * 2048 + (w * 8) * 64;
        #pragma unroll
        for (int j = 0; j < 8; ++j)
            async_copy16(src + j * 64, &Bbuf[buf][(w * 8 + j) * 64]);
    };

    stage(0, 0);   // DMA queued first; A-loads land behind it

    // A fragments: two 32-row tiles (fragment-major, coalesced 1KB loads)
    const bf16x8* Af0 = E1f + (size_t)b * 65536 + (size_t)(rt * 8 + w * 2) * 1024 + l;
    const bf16x8* Af1 = Af0 + 1024;
    bf16x8 af0[16], af1[16];
    #pragma unroll
    for (int kt = 0; kt < 16; ++kt) { af0[kt] = Af0[kt * 64]; af1[kt] = Af1[kt * 64]; }

    float rowAcc0[16], rowAcc1[16];
    #pragma unroll
    for (int r = 0; r < 16; ++r) { rowAcc0[r] = 0.f; rowAcc1[r] = 0.f; }

    // interleaved dual-chain MFMA for one 32-col half
    auto mmpair = [&](f32x16& x0, f32x16& x1, const bf16x8* Bf) {
        #pragma unroll
        for (int r = 0; r < 16; ++r) { x0[r] = 0.f; x1[r] = 0.f; }
        __builtin_amdgcn_s_setprio(1);
        #pragma unroll
        for (int kt = 0; kt < 16; ++kt) {
            bf16x8 bfrag = Bf[kt * 64];
            x0 = __builtin_amdgcn_mfma_f32_32x32x16_bf16(af0[kt], bfrag, x0, 0, 0, 0);
            x1 = __builtin_amdgcn_mfma_f32_32x32x16_bf16(af1[kt], bfrag, x1, 0, 0, 0);
        }
        __builtin_amdgcn_s_setprio(0);
    };

    // epilogue for ONE finished accumulator (32 rows x 32 cols)
    auto epi = [&](const f32x16& c, float (&rAcc)[16], int slot) {
        float p = 0.f;
        #pragma unroll
        for (int r = 0; r < 16; ++r) {
            float e = __builtin_amdgcn_exp2f(c[r]);
            rAcc[r] += e;
            p += e;
        }
        p += __shfl_xor(p, 32);                 // fold 16-row halves
        if (l < 32) colLDS[w * 512 + slot * 32 + l] += p;
    };

    f32x16 c0, c1, d0, d1;
    #pragma unroll
    for (int r = 0; r < 16; ++r) d1[r] = -__builtin_inff();  // exp2 -> 0

    __syncthreads();   // stage(0) + A-frags complete

    for (int sg = 0; sg < 8; ++sg) {
        if (sg < 7) stage((sg + 1) & 1, sg + 1);
        const bf16x8* Bf = Bbuf[sg & 1] + l;

        mmpair(c0, c1, Bf);                       // half 0
        epi(d1, rowAcc1, (sg * 2 - 1) & 15);      // prev d1 (no copy): overlaps chain 0
        epi(c0, rowAcc0, sg * 2);

        mmpair(d0, d1, Bf + 1024);                // half 1 (re-inits d1 AFTER its epi)
        epi(c1, rowAcc1, sg * 2);                 // overlaps chain 1
        epi(d0, rowAcc0, sg * 2 + 1);
        // d1 stays live across the barrier; finished next iteration

        __syncthreads();
    }
    epi(d1, rowAcc1, 15);                         // drain

    // row sums: reduce across 32 column-lanes
    #pragma unroll
    for (int r = 0; r < 16; ++r) {
        #pragma unroll
        for (int off = 1; off <= 16; off <<= 1) {
            rowAcc0[r] += __shfl_xor(rowAcc0[r], off);
            rowAcc1[r] += __shfl_xor(rowAcc1[r], off);
        }
    }
    if ((l & 31) == 0) {
        // C/D layout: row = (r&3) + 8*(r>>2) + 4*(lane>>5); plain stores
        float* rs = rowPart + (size_t)(b * 4 + ct) * 2048 + rt * 256 + w * 64 + 4 * (l >> 5);
        #pragma unroll
        for (int r = 0; r < 16; ++r) {
            const int rl = (r & 3) + 8 * (r >> 2);
            rs[rl]      = rowAcc0[r];
            rs[rl + 32] = rowAcc1[r];
        }
    }

    __syncthreads();   // before cross-wave colLDS fold
    float* gcol = colPart + (size_t)((b * 4 + ct) * 8 + rt) * 512;
    for (int i = tid; i < 512; i += 256)
        gcol[i] = colLDS[i] + colLDS[512 + i] + colLDS[1024 + i] + colLDS[1536 + i];

    // ------------------- fused finalize (fin folded in) -------------------
    __threadfence();                 // publish this block's partials (agent)
    __syncthreads();
    if (tid == 0) {
        isLastS = 0u;
        rrS = atomicAdd(&cntRow[b * 8 + rt], 1u);
        rcS = atomicAdd(&cntCol[b * 4 + ct], 1u);
    }
    __syncthreads();
    const bool doRow = (rrS == 3u), doCol = (rcS == 7u);
    if (doRow || doCol) __threadfence();         // acquire side

    auto blockSum = [&](float v) {               // 256-thread sum -> all
        #pragma unroll
        for (int off = 1; off <= 32; off <<= 1) v += __shfl_xor(v, off);
        if (l == 0) redbuf[w] = v;
        __syncthreads();
        float t = redbuf[0] + redbuf[1] + redbuf[2] + redbuf[3];
        __syncthreads();
        return t;
    };

    if (doRow) {   // 4th ct-block of (b, rt): 256 row log-sums
        const float* rp = rowPart + (size_t)(b * 4) * 2048 + rt * 256 + tid;
        float rsum = aload(rp) + aload(rp + 2048) + aload(rp + 4096) + aload(rp + 6144);
        float t = blockSum(logf(rsum));
        if (tid == 0) {
            atomicAdd(scalars, t);
            __threadfence();
            if (atomicAdd(cnt2, 1u) == 191u) isLastS = 1u;
        }
    }
    if (doCol) {   // 8th rt-block of (b, ct): 512 col log-sums
        float s = 0.f;
        #pragma unroll
        for (int k = 0; k < 2; ++k) {
            const float* cp = colPart + (size_t)((b * 4 + ct) * 8) * 512 + k * 256 + tid;
            float cs = 0.f;
            #pragma unroll
            for (int r8 = 0; r8 < 8; ++r8) cs += aload(cp + r8 * 512);
            s += logf(cs);
        }
        float t = blockSum(s);
        if (tid == 0) {
            atomicAdd(scalars, t);
            __threadfence();
            if (atomicAdd(cnt2, 1u) == 191u) isLastS = 1u;
        }
    }
    __syncthreads();
    if (isLastS) {   // 192nd group contribution: diag term + output
        float d = diagPart[tid] + diagPart[tid + 256]
                + diagPart[tid + 512] + diagPart[tid + 768];
        #pragma unroll
        for (int off = 1; off <= 32; off <<= 1) d += __shfl_xor(d, off);
        if (l == 0) redbuf[w] = d;
        __syncthreads();
        if (tid == 0) {
            const float diag = redbuf[0] + redbuf[1] + redbuf[2] + redbuf[3];
            const float logSum = atomicAdd(scalars, 0.f);  // coherent read
            out[0] = (logSum - 2.0f * diag) / (float)NTOT;
        }
    }
}

// ---------------------------------------------------------------------------
extern "C" void kernel_launch(void* const* d_in, const int* in_sizes, int n_in,
                              void* d_out, int out_size, void* d_ws, size_t ws_size,
                              hipStream_t stream) {
    const float* A = (const float*)d_in[0];
    const float* B = (const float*)d_in[1];

    char* w = (char*)d_ws;
    uint4* E1f = (uint4*)w;                                    // 16 MB
    uint4* E2f = (uint4*)(w + (size_t)16 * 1024 * 1024);       // 16 MB
    float* colPart = (float*)(w + (size_t)32 * 1024 * 1024);   // 262144 f (1 MB)
    float* rowPart = colPart + 262144;                         // 131072 f (0.5 MB)
    float* diagPart = rowPart + 131072;                        // 1024 f
    float* scalars = diagPart + 1024;                          // [logSum]
    unsigned int* cnts = (unsigned int*)(scalars + 1);         // 193 u32

    hipLaunchKernelGGL(nrm_kernel, dim3(1024), dim3(256), 0, stream,
                       A, B, E1f, E2f, diagPart, scalars, cnts);
    hipLaunchKernelGGL(gemm_kernel, dim3(512), dim3(256), 0, stream,
                       (const bf16x8*)E1f, (const uint4*)E2f, colPart, rowPart,
                       diagPart, scalars, cnts, (float*)d_out);
}

// Round 12
// 137.863 us; speedup vs baseline: 1.3294x; 1.3294x over previous
//
#include <hip/hip_runtime.h>
#include <hip/hip_bf16.h>

typedef __attribute__((ext_vector_type(8))) __bf16 bf16x8;
typedef __attribute__((ext_vector_type(16))) float f32x16;

#define SCALE_L2E 14.4269504088896f // 10 * log2(e)
#define NTOT 32768

#define AS_GLOBAL __attribute__((address_space(1)))
#define AS_LDS    __attribute__((address_space(3)))

__device__ inline void async_copy16(const void* g, void* l) {
    __builtin_amdgcn_global_load_lds((const AS_GLOBAL void*)g, (AS_LDS void*)l, 16, 0, 0);
}

// ---------------------------------------------------------------------------
// bf16 pack helpers (RNE)
// ---------------------------------------------------------------------------
__device__ inline unsigned int f2bf(float f) {
    unsigned int u = __builtin_bit_cast(unsigned int, f);
    u += 0x7fffu + ((u >> 16) & 1u);
    return u >> 16;
}

__device__ inline uint4 pack8(float4 x, float4 y, float s) {
    uint4 r;
    r.x = f2bf(x.x * s) | (f2bf(x.y * s) << 16);
    r.y = f2bf(x.z * s) | (f2bf(x.w * s) << 16);
    r.z = f2bf(y.x * s) | (f2bf(y.y * s) << 16);
    r.w = f2bf(y.z * s) | (f2bf(y.w * s) << 16);
    return r;
}

__device__ inline float dot8(float4 x, float4 y) {
    return x.x*y.x + x.y*y.y + x.z*y.z + x.w*y.w;
}

// ---------------------------------------------------------------------------
// Kernel 1: L2-normalize -> bf16 FRAGMENT-MAJOR + fp32 diag partials.
// E1 is PRE-SCALED by 10*log2(e) so gemm's epilogue is exp2(acc).
// Coalesced E-stores via 32KB XOR-swizzled LDS transpose (r10, -13.5us).
// ---------------------------------------------------------------------------
__global__ __launch_bounds__(256) void nrm_kernel(
        const float* __restrict__ A, const float* __restrict__ B,
        uint4* __restrict__ E1f, uint4* __restrict__ E2f,
        float* __restrict__ diagPart, float* __restrict__ scalars,
        unsigned int* __restrict__ counter) {
    __shared__ uint4 E1lds[1024];   // 16 KB
    __shared__ uint4 E2lds[1024];   // 16 KB
    __shared__ float part[4];

    const int tid = threadIdx.x, w = tid >> 6, l = tid & 63;
    const int q = l & 31, h = l >> 5;
    const int wid = blockIdx.x * 4 + w;            // 0..4095, 8 rows each

    const float4* A4 = (const float4*)A + ((size_t)wid * 8 + h) * 64 + q * 2;
    const float4* B4 = (const float4*)B + ((size_t)wid * 8 + h) * 64 + q * 2;

    float4 a[8], bb[8];
    #pragma unroll
    for (int i = 0; i < 4; ++i) {                  // all loads up front (MLP)
        a[2*i]    = A4[i * 128];
        a[2*i+1]  = A4[i * 128 + 1];
        bb[2*i]   = B4[i * 128];
        bb[2*i+1] = B4[i * 128 + 1];
    }

    float ddAcc = 0.f;
    #pragma unroll
    for (int i = 0; i < 4; ++i) {
        float sa = dot8(a[2*i], a[2*i]) + dot8(a[2*i+1], a[2*i+1]);
        float sb = dot8(bb[2*i], bb[2*i]) + dot8(bb[2*i+1], bb[2*i+1]);
        float dd = dot8(a[2*i], bb[2*i]) + dot8(a[2*i+1], bb[2*i+1]);
        #pragma unroll
        for (int off = 1; off <= 16; off <<= 1) {
            sa += __shfl_xor(sa, off);
            sb += __shfl_xor(sb, off);
            dd += __shfl_xor(dd, off);
        }
        const float ia = 1.0f / fmaxf(sqrtf(sa), 1e-12f);
        const float ib = 1.0f / fmaxf(sqrtf(sb), 1e-12f);
        if (q == 0) ddAcc += dd * ia * ib * 10.0f;

        // LDS transpose staging: idx within this block's 32-row group
        const int row32 = w * 8 + i * 2 + h;                 // 0..31
        const int idx   = (q >> 1) * 64 + (q & 1) * 32 + row32;
        const int idxs  = idx ^ ((idx >> 5) & 7);            // bank swizzle
        E1lds[idxs] = pack8(a[2*i], a[2*i+1], ia * SCALE_L2E);  // pre-scaled
        E2lds[idxs] = pack8(bb[2*i], bb[2*i+1], ib);
    }

    #pragma unroll
    for (int off = 1; off <= 32; off <<= 1) ddAcc += __shfl_xor(ddAcc, off);
    if (l == 0) part[w] = ddAcc;
    __syncthreads();   // part[] + E-lds complete

    // coalesced write-out: this block's group is uint4[blockIdx*1024 ..)
    {
        uint4* g1 = E1f + (size_t)blockIdx.x * 1024;
        uint4* g2 = E2f + (size_t)blockIdx.x * 1024;
        #pragma unroll
        for (int j = 0; j < 4; ++j) {
            const int t = j * 256 + tid;
            const int ts = t ^ ((t >> 5) & 7);
            g1[t] = E1lds[ts];
            g2[t] = E2lds[ts];
        }
    }

    if (tid == 0) diagPart[blockIdx.x] = part[0] + part[1] + part[2] + part[3];
    if (blockIdx.x == 0 && tid == 0) { scalars[0] = 0.f; *counter = 0u; }
}

// ---------------------------------------------------------------------------
// Kernel 2: fused GEMM + exp + row/col partials. 512 blocks, 4 waves.
// Block: 256 rows x 512 cols; wave: 64 rows (af0/af1 in regs) x 512 cols.
//
// T4 COUNTED-VMCNT PIPELINE (replaces the full-drain __syncthreads loop):
// 16 steps x 32 cols; B staged into THREE 16 KB buffers, TWO steps ahead.
// Per step: s_waitcnt vmcnt(4) (stage(s) landed, stage(s+1) stays in
// flight) -> raw s_barrier -> stage(s+2) (overwrites buf[(s-1)%3], safe:
// all waves passed the barrier after reading it) -> 32 MFMA -> deferred
// epilogues. Last step peeled with vmcnt(0). LDS 56 KB -> 2 blocks/CU.
// r11's fused-finalize reverted: per-block __threadfence = buffer_wbl2
// L2-flush storm (gemm 45->94us).
// Deferred-epi pipeline, setprio, raw v_exp_f32, -10 shift in fin: as r3.
// ---------------------------------------------------------------------------
__global__ __launch_bounds__(256, 2) void gemm_kernel(
        const bf16x8* __restrict__ E1f, const uint4* __restrict__ E2f,
        float* __restrict__ colPart, float* __restrict__ rowPart) {
    __shared__ bf16x8 Bbuf[3][1024];   // 3 x 16 KB (32 cols each)
    __shared__ float colLDS[2048];     // 4 per-wave slices of 512

    const int tid = threadIdx.x, w = tid >> 6, l = tid & 63;
    const int b = blockIdx.x & 15;             // XCD = b&7 (L2 pinning)
    const int ct = (blockIdx.x >> 4) & 3, rt = blockIdx.x >> 6;

    for (int i = l; i < 512; i += 64) colLDS[w * 512 + i] = 0.f;

    const uint4* Bb = E2f + (size_t)b * 65536 + (size_t)ct * 16384 + l;

    // stage 32-col step s into Bbuf[s%3]; wave w covers 4 chunk-rows
    auto stage = [&](int s) {
        const uint4* src = Bb + (size_t)s * 1024 + (w * 4) * 64;
        #pragma unroll
        for (int j = 0; j < 4; ++j)
            async_copy16(src + j * 64, &Bbuf[s % 3][(w * 4 + j) * 64]);
    };

    stage(0);   // 2-deep prefetch queued first; A-loads land behind it
    stage(1);

    // A fragments: two 32-row tiles (fragment-major, coalesced 1KB loads)
    const bf16x8* Af0 = E1f + (size_t)b * 65536 + (size_t)(rt * 8 + w * 2) * 1024 + l;
    const bf16x8* Af1 = Af0 + 1024;
    bf16x8 af0[16], af1[16];
    #pragma unroll
    for (int kt = 0; kt < 16; ++kt) { af0[kt] = Af0[kt * 64]; af1[kt] = Af1[kt * 64]; }

    float rowAcc0[16], rowAcc1[16];
    #pragma unroll
    for (int r = 0; r < 16; ++r) { rowAcc0[r] = 0.f; rowAcc1[r] = 0.f; }

    // interleaved dual-chain MFMA for one 32-col step
    auto mmpair = [&](f32x16& x0, f32x16& x1, const bf16x8* Bf) {
        #pragma unroll
        for (int r = 0; r < 16; ++r) { x0[r] = 0.f; x1[r] = 0.f; }
        __builtin_amdgcn_s_setprio(1);
        #pragma unroll
        for (int kt = 0; kt < 16; ++kt) {
            bf16x8 bfrag = Bf[kt * 64];
            x0 = __builtin_amdgcn_mfma_f32_32x32x16_bf16(af0[kt], bfrag, x0, 0, 0, 0);
            x1 = __builtin_amdgcn_mfma_f32_32x32x16_bf16(af1[kt], bfrag, x1, 0, 0, 0);
        }
        __builtin_amdgcn_s_setprio(0);
    };

    // epilogue for ONE finished accumulator (32 rows x 32 cols)
    auto epi = [&](const f32x16& c, float (&rAcc)[16], int slot) {
        float p = 0.f;
        #pragma unroll
        for (int r = 0; r < 16; ++r) {
            float e = __builtin_amdgcn_exp2f(c[r]);
            rAcc[r] += e;
            p += e;
        }
        p += __shfl_xor(p, 32);                 // fold 16-row halves
        if (l < 32) colLDS[w * 512 + slot * 32 + l] += p;
    };

    f32x16 c0, c1, d0, d1;
    #pragma unroll
    for (int r = 0; r < 16; ++r) d1[r] = -__builtin_inff();  // exp2 -> 0

    // steps 0..13 (pairs); counted vmcnt: stage(s) done, stage(s+1) in flight
    for (int sp = 0; sp < 7; ++sp) {
        const int s0 = sp * 2, s1 = sp * 2 + 1;

        asm volatile("s_waitcnt vmcnt(4)" ::: "memory");
        __builtin_amdgcn_s_barrier();
        stage(s0 + 2);
        mmpair(c0, c1, Bbuf[s0 % 3] + l);
        epi(d1, rowAcc1, (s0 - 1) & 15);      // prev step's deferred acc
        epi(c0, rowAcc0, s0);

        asm volatile("s_waitcnt vmcnt(4)" ::: "memory");
        __builtin_amdgcn_s_barrier();
        stage(s1 + 2);
        mmpair(d0, d1, Bbuf[s1 % 3] + l);     // re-inits d1 AFTER its epi
        epi(c1, rowAcc1, s1 - 1);
        epi(d0, rowAcc0, s1);
    }
    // step 14 (no more staging; stage(15) still in flight)
    asm volatile("s_waitcnt vmcnt(4)" ::: "memory");
    __builtin_amdgcn_s_barrier();
    mmpair(c0, c1, Bbuf[14 % 3] + l);
    epi(d1, rowAcc1, 13);
    epi(c0, rowAcc0, 14);
    // step 15 (final: full drain)
    asm volatile("s_waitcnt vmcnt(0)" ::: "memory");
    __builtin_amdgcn_s_barrier();
    mmpair(d0, d1, Bbuf[15 % 3] + l);
    epi(c1, rowAcc1, 14);
    epi(d0, rowAcc0, 15);
    epi(d1, rowAcc1, 15);                     // drain pipeline

    // row sums: reduce across 32 column-lanes
    #pragma unroll
    for (int r = 0; r < 16; ++r) {
        #pragma unroll
        for (int off = 1; off <= 16; off <<= 1) {
            rowAcc0[r] += __shfl_xor(rowAcc0[r], off);
            rowAcc1[r] += __shfl_xor(rowAcc1[r], off);
        }
    }
    if ((l & 31) == 0) {
        // C/D layout: row = (r&3) + 8*(r>>2) + 4*(lane>>5); plain stores
        float* rs = rowPart + (size_t)(b * 4 + ct) * 2048 + rt * 256 + w * 64 + 4 * (l >> 5);
        #pragma unroll
        for (int r = 0; r < 16; ++r) {
            const int rl = (r & 3) + 8 * (r >> 2);
            rs[rl]      = rowAcc0[r];
            rs[rl + 32] = rowAcc1[r];
        }
    }

    __syncthreads();   // full barrier before cross-wave colLDS fold
    float* gcol = colPart + (size_t)((b * 4 + ct) * 8 + rt) * 512;
    for (int i = tid; i < 512; i += 256)
        gcol[i] = colLDS[i] + colLDS[512 + i] + colLDS[1024 + i] + colLDS[1536 + i];
}

// ---------------------------------------------------------------------------
// Kernel 3: fold partials, sum logs, last block finalizes.
// gemm computes exp2(acc) (no -SCALE_L2E shift); each of the 2*32768 log
// terms is larger by exactly 10.0, cancelling the former "+ 20.0f".
// ---------------------------------------------------------------------------
__global__ __launch_bounds__(256) void fin_kernel(
        const float* __restrict__ colPart, const float* __restrict__ rowPart,
        const float* __restrict__ diagPart, float* __restrict__ scalars,
        unsigned int* __restrict__ counter, float* __restrict__ out) {
    const int tid = threadIdx.x;
    float s = 0.f;
    #pragma unroll
    for (int k = 0; k < 2; ++k) {
        const int g = blockIdx.x * 512 + k * 256 + tid;
        // column g: b = g>>11, ct = (g>>9)&3, c = g&511
        const float* cp = colPart + (size_t)(((g >> 11) * 4 + ((g >> 9) & 3)) * 8) * 512 + (g & 511);
        float cs = 0.f;
        #pragma unroll
        for (int rt = 0; rt < 8; ++rt) cs += cp[rt * 512];
        // row g: b = g>>11, r = g&2047
        const float* rp = rowPart + (size_t)(g >> 11) * 4 * 2048 + (g & 2047);
        float rsum = rp[0] + rp[2048] + rp[4096] + rp[6144];
        s += logf(cs) + logf(rsum);
    }
    #pragma unroll
    for (int off = 1; off <= 32; off <<= 1) s += __shfl_xor(s, off);
    __shared__ float part[4];
    __shared__ unsigned int lastFlag;
    if ((tid & 63) == 0) part[tid >> 6] = s;
    __syncthreads();
    if (tid == 0) {
        atomicAdd(&scalars[0], part[0] + part[1] + part[2] + part[3]);
        __threadfence();
        lastFlag = (atomicAdd(counter, 1u) == 63u) ? 1u : 0u;
    }
    __syncthreads();
    if (lastFlag) {
        float d = diagPart[tid] + diagPart[tid + 256]
                + diagPart[tid + 512] + diagPart[tid + 768];
        #pragma unroll
        for (int off = 1; off <= 32; off <<= 1) d += __shfl_xor(d, off);
        if ((tid & 63) == 0) part[tid >> 6] = d;
        __syncthreads();
        if (tid == 0) {
            const float diag = part[0] + part[1] + part[2] + part[3];
            const float logSum = atomicAdd(&scalars[0], 0.f);  // coherent read
            out[0] = (logSum - 2.0f * diag) / (float)NTOT;
        }
    }
}

// ---------------------------------------------------------------------------
extern "C" void kernel_launch(void* const* d_in, const int* in_sizes, int n_in,
                              void* d_out, int out_size, void* d_ws, size_t ws_size,
                              hipStream_t stream) {
    const float* A = (const float*)d_in[0];
    const float* B = (const float*)d_in[1];

    char* w = (char*)d_ws;
    uint4* E1f = (uint4*)w;                                    // 16 MB
    uint4* E2f = (uint4*)(w + (size_t)16 * 1024 * 1024);       // 16 MB
    float* colPart = (float*)(w + (size_t)32 * 1024 * 1024);   // 262144 f (1 MB)
    float* rowPart = colPart + 262144;                         // 131072 f (0.5 MB)
    float* diagPart = rowPart + 131072;                        // 1024 f
    float* scalars = diagPart + 1024;                          // [logSum]
    unsigned int* counter = (unsigned int*)(scalars + 1);

    hipLaunchKernelGGL(nrm_kernel, dim3(1024), dim3(256), 0, stream,
                       A, B, E1f, E2f, diagPart, scalars, counter);
    hipLaunchKernelGGL(gemm_kernel, dim3(512), dim3(256), 0, stream,
                       (const bf16x8*)E1f, (const uint4*)E2f, colPart, rowPart);
    hipLaunchKernelGGL(fin_kernel, dim3(64), dim3(256), 0, stream,
                       colPart, rowPart, diagPart, scalars, counter, (float*)d_out);
}